// Round 1
// baseline (485.503 us; speedup 1.0000x reference)
//
#include <hip/hip_runtime.h>
#include <hip/hip_bf16.h>
#include <math.h>

// MoE gate: logits = h(16384x4096) @ w(64x4096)^T + bias; softmax; top-2;
// renormalize. Output: [topk_w (16384x2 f32) ; topk_idx (16384x2 as f32)].
//
// R5: latency-bound fix (all pipes <10%, occupancy 36.5% in R4 counters).
// Keep R4's split-precision bf16 MFMA numerics EXACTLY (hihi acc + separate
// cross acc; logit err ~1.5e-6 class), but re-tile for 100% occupancy:
//   - 512-thread blocks (8 waves), wave = (K-quarter q, shard-half jh).
//     Each wave: 32 steps over its 1024-float K slice, 2 shard tiles.
//     acc = 2x(2 f32x4) = 16 regs (was 32) -> total fits 64-VGPR cap for
//     8 waves/SIMD (__launch_bounds__(512,8)) = 32 waves/CU.
//   - jh=0/1 waves of a quarter read identical h lines on the same CU ->
//     L1 hit for the second; HBM h traffic unchanged (256 MB stream).
//   - Full unroll: h step offsets (<=3968B) and w step offsets (<=1984B)
//     fold into global-load immediates; loop body = loads + cvt + MFMA only,
//     scheduler free to keep several steps' loads in flight.
//   - bf16 RN split via bit-twiddle (exact same results for finite inputs).
// LDS partial layout + epilogue reduce identical to R4 ([4][16][68], 4
// K-quarter partials, fused top-2 + softmax-cancel).
// Floor: h stream 256 MB / 6.3 TB/s = 41 us.

#define HIDDEN 4096
#define NSHARD 64
#define B_ROWS 16384

typedef short bf16x8 __attribute__((ext_vector_type(8)));
typedef float f32x4  __attribute__((ext_vector_type(4)));

__device__ __forceinline__ unsigned short f32_to_bf16_rn(float f) {
    __hip_bfloat16 h = __float2bfloat16(f);          // round-to-nearest
    return *reinterpret_cast<unsigned short*>(&h);
}
__device__ __forceinline__ float bf16_bits_to_f32(unsigned short u) {
    union { unsigned int i; float f; } v; v.i = ((unsigned int)u) << 16;
    return v.f;
}

// Exact RN bf16 split, bit-twiddled (== __float2bfloat16 for finite non-NaN).
__device__ __forceinline__ void bf16_split(float f, short* hi, short* lo) {
    const unsigned int u = __float_as_uint(f);
    const unsigned int r = u + 0x7fffu + ((u >> 16) & 1u);
    *hi = (short)(r >> 16);
    union { unsigned int i; float f2; } hv; hv.i = r & 0xffff0000u;
    const float res = f - hv.f2;                     // exact in f32
    const unsigned int u2 = __float_as_uint(res);
    *lo = (short)((u2 + 0x7fffu + ((u2 >> 16) & 1u)) >> 16);
}

// ---- kernel 1: split w into bf16 hi/lo (d_ws rewritten every launch) ----
__global__ __launch_bounds__(256)
void wsplit_kernel(const float* __restrict__ w,
                   unsigned short* __restrict__ w_hi,
                   unsigned short* __restrict__ w_lo)
{
    const int idx = (blockIdx.x * 256 + threadIdx.x) * 4;
    const float4 v = *(const float4*)(w + idx);
    const float a[4] = {v.x, v.y, v.z, v.w};
    ushort4 hi, lo;
    unsigned short hb;
    hb = f32_to_bf16_rn(a[0]); hi.x = hb; lo.x = f32_to_bf16_rn(a[0] - bf16_bits_to_f32(hb));
    hb = f32_to_bf16_rn(a[1]); hi.y = hb; lo.y = f32_to_bf16_rn(a[1] - bf16_bits_to_f32(hb));
    hb = f32_to_bf16_rn(a[2]); hi.z = hb; lo.z = f32_to_bf16_rn(a[2] - bf16_bits_to_f32(hb));
    hb = f32_to_bf16_rn(a[3]); hi.w = hb; lo.w = f32_to_bf16_rn(a[3] - bf16_bits_to_f32(hb));
    *(ushort4*)(w_hi + idx) = hi;
    *(ushort4*)(w_lo + idx) = lo;
}

// ---- kernel 2: the gate ----
__global__ __launch_bounds__(512, 8)
void gate_kernel(const float* __restrict__ h,
                 const unsigned short* __restrict__ w_hi,
                 const unsigned short* __restrict__ w_lo,
                 const float* __restrict__ bias,
                 float* __restrict__ out)
{
    __shared__ float lsum[4][16][68];   // [K-quarter][row][shard], pad 68

    const int tid  = threadIdx.x;
    const int lane = tid & 63;
    const int wv   = tid >> 6;          // wave 0..7
    const int q    = wv >> 1;           // K quarter 0..3
    const int jh   = wv & 1;            // shard half: tiles jh*2, jh*2+1
    const int m    = lane & 15;         // A row within tile / B shard within tile
    const int quad = lane >> 4;         // k-subgroup: k = quad*8 + j
    const int row0 = blockIdx.x * 16;

    const float* __restrict__ aptr =
        h + (size_t)(row0 + m) * HIDDEN + q * 1024 + quad * 8;
    const size_t boff = (size_t)m * HIDDEN + q * 1024 + quad * 8;
    const unsigned short* __restrict__ bh0p = w_hi + boff + (size_t)(jh * 2 + 0) * 16 * HIDDEN;
    const unsigned short* __restrict__ bh1p = w_hi + boff + (size_t)(jh * 2 + 1) * 16 * HIDDEN;
    const unsigned short* __restrict__ bl0p = w_lo + boff + (size_t)(jh * 2 + 0) * 16 * HIDDEN;
    const unsigned short* __restrict__ bl1p = w_lo + boff + (size_t)(jh * 2 + 1) * 16 * HIDDEN;

    f32x4 acch[2], accx[2];             // [local shard tile]: hihi / cross
#pragma unroll
    for (int j = 0; j < 2; ++j) {
        acch[j] = (f32x4)0.0f;
        accx[j] = (f32x4)0.0f;
    }

#pragma unroll
    for (int step = 0; step < 32; ++step) {
        // h first (HBM, longest latency), then w (L2-resident).
        const float4 a0 = *(const float4*)(aptr + step * 32);
        const float4 a1 = *(const float4*)(aptr + step * 32 + 4);
        const bf16x8 bh0 = *(const bf16x8*)(bh0p + step * 32);
        const bf16x8 bh1 = *(const bf16x8*)(bh1p + step * 32);
        const bf16x8 bl0 = *(const bf16x8*)(bl0p + step * 32);
        const bf16x8 bl1 = *(const bf16x8*)(bl1p + step * 32);

        const float av[8] = {a0.x, a0.y, a0.z, a0.w, a1.x, a1.y, a1.z, a1.w};
        bf16x8 ahi, alo;
#pragma unroll
        for (int i = 0; i < 8; ++i) {
            short hb, lb;
            bf16_split(av[i], &hb, &lb);
            ahi[i] = hb;
            alo[i] = lb;
        }

        acch[0] = __builtin_amdgcn_mfma_f32_16x16x32_bf16(ahi, bh0, acch[0], 0, 0, 0);
        acch[1] = __builtin_amdgcn_mfma_f32_16x16x32_bf16(ahi, bh1, acch[1], 0, 0, 0);
        accx[0] = __builtin_amdgcn_mfma_f32_16x16x32_bf16(alo, bh0, accx[0], 0, 0, 0);
        accx[1] = __builtin_amdgcn_mfma_f32_16x16x32_bf16(alo, bh1, accx[1], 0, 0, 0);
        accx[0] = __builtin_amdgcn_mfma_f32_16x16x32_bf16(ahi, bl0, accx[0], 0, 0, 0);
        accx[1] = __builtin_amdgcn_mfma_f32_16x16x32_bf16(ahi, bl1, accx[1], 0, 0, 0);
        accx[0] = __builtin_amdgcn_mfma_f32_16x16x32_bf16(alo, bl0, accx[0], 0, 0, 0);
        accx[1] = __builtin_amdgcn_mfma_f32_16x16x32_bf16(alo, bl1, accx[1], 0, 0, 0);
    }

    // C/D layout (m89-verified): col = lane&15 (shard), row = quad*4 + reg.
    // Wave (q,jh) owns shards [jh*32, jh*32+32) of K-quarter q.
#pragma unroll
    for (int j = 0; j < 2; ++j)
#pragma unroll
        for (int p = 0; p < 4; ++p)
            lsum[q][quad * 4 + p][(jh * 2 + j) * 16 + m] = acch[j][p] + accx[j][p];

    __syncthreads();

    // ---- reduce 4 K-quarters + bias; fused top-2 (threads 0..255) ----
    if (tid < 256) {
        const int row = tid >> 4;           // 0..15
        const int s   = tid & 15;           // shard group: shards s*4..s*4+3
        float4 vs = *(const float4*)&lsum[0][row][s * 4];
        {
            const float4 v1 = *(const float4*)&lsum[1][row][s * 4];
            const float4 v2 = *(const float4*)&lsum[2][row][s * 4];
            const float4 v3 = *(const float4*)&lsum[3][row][s * 4];
            vs.x += v1.x + v2.x + v3.x;
            vs.y += v1.y + v2.y + v3.y;
            vs.z += v1.z + v2.z + v3.z;
            vs.w += v1.w + v2.w + v3.w;
        }
        const float4 bv = *(const float4*)(bias + s * 4);
        const float v0 = vs.x + bv.x, v1 = vs.y + bv.y;
        const float v2 = vs.z + bv.z, v3 = vs.w + bv.w;

        // per-thread top-2 over 4 shards (ascending idx: first-occurrence ties)
        float m1 = v0, m2 = -INFINITY;
        int   i1 = s * 4, i2 = 0;
        if (v1 > m1)      { m2 = m1; i2 = i1; m1 = v1; i1 = s * 4 + 1; }
        else              { m2 = v1; i2 = s * 4 + 1; }
        if (v2 > m1)      { m2 = m1; i2 = i1; m1 = v2; i1 = s * 4 + 2; }
        else if (v2 > m2) { m2 = v2; i2 = s * 4 + 2; }
        if (v3 > m1)      { m2 = m1; i2 = i1; m1 = v3; i1 = s * 4 + 3; }
        else if (v3 > m2) { m2 = v3; i2 = s * 4 + 3; }

        // merge across the 16 shard-groups (lane bits 0..3), index tie-break
#pragma unroll
        for (int msk = 1; msk <= 8; msk <<= 1) {
            const float o1 = __shfl_xor(m1, msk, 64);
            const int   q1 = __shfl_xor(i1, msk, 64);
            const float o2 = __shfl_xor(m2, msk, 64);
            const int   q2 = __shfl_xor(i2, msk, 64);
            const bool take = (o1 > m1) || (o1 == m1 && q1 < i1);
            const float w1 = take ? o1 : m1; const int w1i = take ? q1 : i1;
            const float l1 = take ? m1 : o1; const int l1i = take ? i1 : q1;
            const float s2 = take ? o2 : m2; const int s2i = take ? q2 : i2;
            const bool t2 = (l1 > s2) || (l1 == s2 && l1i < s2i);
            m1 = w1; i1 = w1i;
            m2 = t2 ? l1 : s2; i2 = t2 ? l1i : s2i;
        }

        if (s == 0) {
            const int orow = row0 + row;
            const float ed  = expf(m2 - m1);      // softmax Z cancels
            const float inv = 1.0f / (1.0f + ed);
            out[2 * orow + 0] = inv;
            out[2 * orow + 1] = ed * inv;
            float* __restrict__ oidx = out + 2 * B_ROWS;
            oidx[2 * orow + 0] = (float)i1;
            oidx[2 * orow + 1] = (float)i2;
        }
    }
}

extern "C" void kernel_launch(void* const* d_in, const int* in_sizes, int n_in,
                              void* d_out, int out_size, void* d_ws, size_t ws_size,
                              hipStream_t stream)
{
    const float* h    = (const float*)d_in[0];
    const float* wt   = (const float*)d_in[1];
    const float* bias = (const float*)d_in[2];
    float* out = (float*)d_out;

    unsigned short* w_hi = (unsigned short*)d_ws;                    // 512 KB
    unsigned short* w_lo = w_hi + (size_t)NSHARD * HIDDEN;           // 512 KB

    wsplit_kernel<<<dim3(NSHARD * HIDDEN / 1024), dim3(256), 0, stream>>>(wt, w_hi, w_lo);
    gate_kernel<<<dim3(B_ROWS / 16), dim3(512), 0, stream>>>(h, w_hi, w_lo, bias, out);
}

// Round 2
// 428.100 us; speedup vs baseline: 1.1341x; 1.1341x over previous
//
#include <hip/hip_runtime.h>
#include <hip/hip_bf16.h>
#include <math.h>

// MoE gate: logits = h(16384x4096) @ w(64x4096)^T + bias; softmax; top-2;
// renormalize. Output: [topk_w (16384x2 f32) ; topk_idx (16384x2 as f32)].
//
// R6: R5 went latency-bound-by-register-starvation: __launch_bounds__(512,8)
// pinned 32 VGPR -> compiler serialized every load batch (one step's loads
// alone need 24 regs + 16 acc). Occupancy 74% couldn't cover ~700cy exposed
// latency per step. Fix: trade TLP for ILP.
//   - __launch_bounds__(512,4): 128 VGPR cap, 16 waves/CU (50%).
//   - Explicit 2-stage register pipeline, fully unrolled K-loop: step t+1's
//     8 loads issue before step t's split+MFMA (stage idx = step&1, all
//     compile-time -> no scratch).
//   - M=32 rows/block (grid 512): wave = (K-quarter q, shard-half jh) owns
//     2 row-tiles x 2 shard-tiles (acc 32 regs, AGPR-eligible). Halves w
//     re-reads from L2 and VMEM instr count per h-byte vs R5.
//   - Numerics BIT-IDENTICAL to R5: same bf16_split (RN hi + RN lo), same
//     hihi/cross accumulator separation, same q-partial reduce order.
// Floor: h stream 256 MB / 6.3 TB/s = 41 us.

#define HIDDEN 4096
#define NSHARD 64
#define B_ROWS 16384

typedef short bf16x8 __attribute__((ext_vector_type(8)));
typedef float f32x4  __attribute__((ext_vector_type(4)));

__device__ __forceinline__ unsigned short f32_to_bf16_rn(float f) {
    __hip_bfloat16 h = __float2bfloat16(f);          // round-to-nearest
    return *reinterpret_cast<unsigned short*>(&h);
}
__device__ __forceinline__ float bf16_bits_to_f32(unsigned short u) {
    union { unsigned int i; float f; } v; v.i = ((unsigned int)u) << 16;
    return v.f;
}

// Exact RN bf16 split, bit-twiddled (== __float2bfloat16 for finite non-NaN).
__device__ __forceinline__ void bf16_split(float f, short* hi, short* lo) {
    const unsigned int u = __float_as_uint(f);
    const unsigned int r = u + 0x7fffu + ((u >> 16) & 1u);
    *hi = (short)(r >> 16);
    union { unsigned int i; float f2; } hv; hv.i = r & 0xffff0000u;
    const float res = f - hv.f2;                     // exact in f32
    const unsigned int u2 = __float_as_uint(res);
    *lo = (short)((u2 + 0x7fffu + ((u2 >> 16) & 1u)) >> 16);
}

// ---- kernel 1: split w into bf16 hi/lo (d_ws rewritten every launch) ----
__global__ __launch_bounds__(256)
void wsplit_kernel(const float* __restrict__ w,
                   unsigned short* __restrict__ w_hi,
                   unsigned short* __restrict__ w_lo)
{
    const int idx = (blockIdx.x * 256 + threadIdx.x) * 4;
    const float4 v = *(const float4*)(w + idx);
    const float a[4] = {v.x, v.y, v.z, v.w};
    ushort4 hi, lo;
    unsigned short hb;
    hb = f32_to_bf16_rn(a[0]); hi.x = hb; lo.x = f32_to_bf16_rn(a[0] - bf16_bits_to_f32(hb));
    hb = f32_to_bf16_rn(a[1]); hi.y = hb; lo.y = f32_to_bf16_rn(a[1] - bf16_bits_to_f32(hb));
    hb = f32_to_bf16_rn(a[2]); hi.z = hb; lo.z = f32_to_bf16_rn(a[2] - bf16_bits_to_f32(hb));
    hb = f32_to_bf16_rn(a[3]); hi.w = hb; lo.w = f32_to_bf16_rn(a[3] - bf16_bits_to_f32(hb));
    *(ushort4*)(w_hi + idx) = hi;
    *(ushort4*)(w_lo + idx) = lo;
}

// ---- kernel 2: the gate ----
__global__ __launch_bounds__(512, 4)
void gate_kernel(const float* __restrict__ h,
                 const unsigned short* __restrict__ w_hi,
                 const unsigned short* __restrict__ w_lo,
                 const float* __restrict__ bias,
                 float* __restrict__ out)
{
    __shared__ float lsum[4][32][68];   // [K-quarter][row][shard], pad 68

    const int tid  = threadIdx.x;
    const int lane = tid & 63;
    const int wv   = tid >> 6;          // wave 0..7
    const int q    = wv >> 1;           // K quarter 0..3
    const int jh   = wv & 1;            // shard half: tiles jh*2, jh*2+1
    const int m    = lane & 15;         // A row within tile / B shard within tile
    const int quad = lane >> 4;         // k-subgroup: k = quad*8 + j
    const int row0 = blockIdx.x * 32;

    const float* __restrict__ aptr0 =
        h + (size_t)(row0 + m) * HIDDEN + q * 1024 + quad * 8;
    const float* __restrict__ aptr1 = aptr0 + (size_t)16 * HIDDEN;
    const size_t boff = (size_t)m * HIDDEN + q * 1024 + quad * 8;
    const unsigned short* __restrict__ bh0p = w_hi + boff + (size_t)(jh * 2 + 0) * 16 * HIDDEN;
    const unsigned short* __restrict__ bh1p = w_hi + boff + (size_t)(jh * 2 + 1) * 16 * HIDDEN;
    const unsigned short* __restrict__ bl0p = w_lo + boff + (size_t)(jh * 2 + 0) * 16 * HIDDEN;
    const unsigned short* __restrict__ bl1p = w_lo + boff + (size_t)(jh * 2 + 1) * 16 * HIDDEN;

    f32x4 acch[2][2], accx[2][2];       // [row tile][shard tile]: hihi / cross
#pragma unroll
    for (int rt = 0; rt < 2; ++rt)
#pragma unroll
        for (int j = 0; j < 2; ++j) {
            acch[rt][j] = (f32x4)0.0f;
            accx[rt][j] = (f32x4)0.0f;
        }

    // 2-stage register pipeline buffers ([stage][...], stage idx static
    // under full unroll so everything stays in registers).
    float4 pa[2][2][2];                 // [stage][row tile][half]
    bf16x8 pbh[2][2], pbl[2][2];        // [stage][shard tile]

#define GATE_LOADS(S, T) do {                                              \
        pa[S][0][0] = *(const float4*)(aptr0 + (T) * 32);                  \
        pa[S][0][1] = *(const float4*)(aptr0 + (T) * 32 + 4);              \
        pa[S][1][0] = *(const float4*)(aptr1 + (T) * 32);                  \
        pa[S][1][1] = *(const float4*)(aptr1 + (T) * 32 + 4);              \
        pbh[S][0]   = *(const bf16x8*)(bh0p + (T) * 32);                   \
        pbh[S][1]   = *(const bf16x8*)(bh1p + (T) * 32);                   \
        pbl[S][0]   = *(const bf16x8*)(bl0p + (T) * 32);                   \
        pbl[S][1]   = *(const bf16x8*)(bl1p + (T) * 32);                   \
    } while (0)

    GATE_LOADS(0, 0);

#pragma unroll
    for (int step = 0; step < 32; ++step) {
        const int cur = step & 1;
        const int nxt = cur ^ 1;
        if (step < 31) GATE_LOADS(nxt, step + 1);

        bf16x8 ahi[2], alo[2];
#pragma unroll
        for (int rt = 0; rt < 2; ++rt) {
            const float av[8] = {pa[cur][rt][0].x, pa[cur][rt][0].y,
                                 pa[cur][rt][0].z, pa[cur][rt][0].w,
                                 pa[cur][rt][1].x, pa[cur][rt][1].y,
                                 pa[cur][rt][1].z, pa[cur][rt][1].w};
#pragma unroll
            for (int i = 0; i < 8; ++i) {
                short hb, lb;
                bf16_split(av[i], &hb, &lb);
                ahi[rt][i] = hb;
                alo[rt][i] = lb;
            }
        }

#pragma unroll
        for (int rt = 0; rt < 2; ++rt)
#pragma unroll
            for (int j = 0; j < 2; ++j) {
                acch[rt][j] = __builtin_amdgcn_mfma_f32_16x16x32_bf16(ahi[rt], pbh[cur][j], acch[rt][j], 0, 0, 0);
                accx[rt][j] = __builtin_amdgcn_mfma_f32_16x16x32_bf16(alo[rt], pbh[cur][j], accx[rt][j], 0, 0, 0);
                accx[rt][j] = __builtin_amdgcn_mfma_f32_16x16x32_bf16(ahi[rt], pbl[cur][j], accx[rt][j], 0, 0, 0);
                accx[rt][j] = __builtin_amdgcn_mfma_f32_16x16x32_bf16(alo[rt], pbl[cur][j], accx[rt][j], 0, 0, 0);
            }
    }
#undef GATE_LOADS

    // C/D layout (m89-verified): col = lane&15 (shard), row = quad*4 + reg.
    // Wave (q,jh) owns row-tiles {0,1} x shard tiles {jh*2, jh*2+1}.
#pragma unroll
    for (int rt = 0; rt < 2; ++rt)
#pragma unroll
        for (int j = 0; j < 2; ++j)
#pragma unroll
            for (int p = 0; p < 4; ++p)
                lsum[q][rt * 16 + quad * 4 + p][(jh * 2 + j) * 16 + m] =
                    acch[rt][j][p] + accx[rt][j][p];

    __syncthreads();

    // ---- reduce 4 K-quarters + bias; fused top-2 (all 512 threads) ----
    {
        const int row = tid >> 4;           // 0..31
        const int s   = tid & 15;           // shard group: shards s*4..s*4+3
        float4 vs = *(const float4*)&lsum[0][row][s * 4];
        {
            const float4 v1 = *(const float4*)&lsum[1][row][s * 4];
            const float4 v2 = *(const float4*)&lsum[2][row][s * 4];
            const float4 v3 = *(const float4*)&lsum[3][row][s * 4];
            vs.x += v1.x + v2.x + v3.x;
            vs.y += v1.y + v2.y + v3.y;
            vs.z += v1.z + v2.z + v3.z;
            vs.w += v1.w + v2.w + v3.w;
        }
        const float4 bv = *(const float4*)(bias + s * 4);
        const float v0 = vs.x + bv.x, v1 = vs.y + bv.y;
        const float v2 = vs.z + bv.z, v3 = vs.w + bv.w;

        // per-thread top-2 over 4 shards (ascending idx: first-occurrence ties)
        float m1 = v0, m2 = -INFINITY;
        int   i1 = s * 4, i2 = 0;
        if (v1 > m1)      { m2 = m1; i2 = i1; m1 = v1; i1 = s * 4 + 1; }
        else              { m2 = v1; i2 = s * 4 + 1; }
        if (v2 > m1)      { m2 = m1; i2 = i1; m1 = v2; i1 = s * 4 + 2; }
        else if (v2 > m2) { m2 = v2; i2 = s * 4 + 2; }
        if (v3 > m1)      { m2 = m1; i2 = i1; m1 = v3; i1 = s * 4 + 3; }
        else if (v3 > m2) { m2 = v3; i2 = s * 4 + 3; }

        // merge across the 16 shard-groups (lane bits 0..3), index tie-break
#pragma unroll
        for (int msk = 1; msk <= 8; msk <<= 1) {
            const float o1 = __shfl_xor(m1, msk, 64);
            const int   q1 = __shfl_xor(i1, msk, 64);
            const float o2 = __shfl_xor(m2, msk, 64);
            const int   q2 = __shfl_xor(i2, msk, 64);
            const bool take = (o1 > m1) || (o1 == m1 && q1 < i1);
            const float w1 = take ? o1 : m1; const int w1i = take ? q1 : i1;
            const float l1 = take ? m1 : o1; const int l1i = take ? i1 : q1;
            const float s2 = take ? o2 : m2; const int s2i = take ? q2 : i2;
            const bool t2 = (l1 > s2) || (l1 == s2 && l1i < s2i);
            m1 = w1; i1 = w1i;
            m2 = t2 ? l1 : s2; i2 = t2 ? l1i : s2i;
        }

        if (s == 0) {
            const int orow = row0 + row;
            const float ed  = expf(m2 - m1);      // softmax Z cancels
            const float inv = 1.0f / (1.0f + ed);
            out[2 * orow + 0] = inv;
            out[2 * orow + 1] = ed * inv;
            float* __restrict__ oidx = out + 2 * B_ROWS;
            oidx[2 * orow + 0] = (float)i1;
            oidx[2 * orow + 1] = (float)i2;
        }
    }
}

extern "C" void kernel_launch(void* const* d_in, const int* in_sizes, int n_in,
                              void* d_out, int out_size, void* d_ws, size_t ws_size,
                              hipStream_t stream)
{
    const float* h    = (const float*)d_in[0];
    const float* wt   = (const float*)d_in[1];
    const float* bias = (const float*)d_in[2];
    float* out = (float*)d_out;

    unsigned short* w_hi = (unsigned short*)d_ws;                    // 512 KB
    unsigned short* w_lo = w_hi + (size_t)NSHARD * HIDDEN;           // 512 KB

    wsplit_kernel<<<dim3(NSHARD * HIDDEN / 1024), dim3(256), 0, stream>>>(wt, w_hi, w_lo);
    gate_kernel<<<dim3(B_ROWS / 32), dim3(512), 0, stream>>>(h, w_hi, w_lo, bias, out);
}